// Round 3
// baseline (157.056 us; speedup 1.0000x reference)
//
#include <hip/hip_runtime.h>
#include <hip/hip_bf16.h>

#define N_TOK 8192
#define D_IN  1024
#define DK    128
#define NT    256   // number of 32-row q tiles

typedef __attribute__((ext_vector_type(8))) short short8;
typedef __attribute__((ext_vector_type(4))) float f32x4;

static __device__ __forceinline__ unsigned short f2bf(float f) {
    __hip_bfloat16 h = __float2bfloat16(f);
    return __builtin_bit_cast(unsigned short, h);
}

// ---------------- one-time W transpose: W[k][n] f32 -> Wt[n][k] bf16 ----------------
__global__ __launch_bounds__(256) void wtrans_kernel(
    const float* __restrict__ Wq, const float* __restrict__ Wk,
    const float* __restrict__ Wv, unsigned short* __restrict__ Wt)
{
    __shared__ unsigned short T[64][72];
    const int proj = blockIdx.y;
    const float* W = (proj == 0) ? Wq : (proj == 1) ? Wk : Wv;
    unsigned short* out = Wt + (size_t)proj * DK * D_IN;
    const int k0 = (blockIdx.x & 15) * 64, n0 = (blockIdx.x >> 4) * 64;
    const int tid = threadIdx.x;
    #pragma unroll
    for (int i = 0; i < 4; i++) {
        int e = tid + i * 256;
        int r = e >> 4, c4 = e & 15;
        float4 v = *reinterpret_cast<const float4*>(&W[(size_t)(k0 + r) * DK + n0 + c4 * 4]);
        T[c4 * 4 + 0][r] = f2bf(v.x);
        T[c4 * 4 + 1][r] = f2bf(v.y);
        T[c4 * 4 + 2][r] = f2bf(v.z);
        T[c4 * 4 + 3][r] = f2bf(v.w);
    }
    __syncthreads();
    #pragma unroll
    for (int i = 0; i < 4; i++) {
        int e = tid + i * 256;
        int r = e >> 4, c4 = e & 15;
        *reinterpret_cast<ushort4*>(&out[(size_t)(n0 + r) * D_IN + k0 + c4 * 4]) =
            *reinterpret_cast<const ushort4*>(&T[r][c4 * 4]);
    }
}

// ---------------- QKV projection: out = X @ W + b, bf16 outputs ----------------
// BM=64 -> grid (128, 3) = 384 blocks. A staged via LDS; B from bf16 Wt (L2).
__global__ __launch_bounds__(256) void proj_kernel(
    const float* __restrict__ X, const unsigned short* __restrict__ Wt,
    const float* __restrict__ bq, const float* __restrict__ bk,
    const float* __restrict__ bv,
    unsigned short* __restrict__ Qb, unsigned short* __restrict__ Kb,
    unsigned short* __restrict__ Vt)
{
    __shared__ unsigned short As[64][72];

    const int tid  = threadIdx.x;
    const int wid  = tid >> 6, lane = tid & 63;
    const int g    = lane >> 4, r16 = lane & 15;
    const int wm   = wid >> 1, wn = wid & 1;   // wave tile: 32 rows x 64 cols
    const int mb   = blockIdx.x * 64;
    const int proj = blockIdx.y;

    const unsigned short* Wtp = Wt + (size_t)proj * DK * D_IN;
    const float* bias = (proj == 0) ? bq : (proj == 1) ? bk : bv;

    f32x4 acc[2][4] = {};

    for (int k0 = 0; k0 < D_IN; k0 += 64) {
        #pragma unroll
        for (int i = 0; i < 4; i++) {
            int e = tid + i * 256;          // 1024 float4s
            int r = e >> 4, c4 = e & 15;
            const float4 v = *reinterpret_cast<const float4*>(
                &X[(size_t)(mb + r) * D_IN + k0 + c4 * 4]);
            ushort4 h;
            h.x = f2bf(v.x); h.y = f2bf(v.y); h.z = f2bf(v.z); h.w = f2bf(v.w);
            *reinterpret_cast<ushort4*>(&As[r][c4 * 4]) = h;
        }
        __syncthreads();
        #pragma unroll
        for (int kk = 0; kk < 64; kk += 32) {
            short8 af[2], bfr[4];
            #pragma unroll
            for (int mi = 0; mi < 2; mi++)
                af[mi] = *reinterpret_cast<const short8*>(&As[wm * 32 + mi * 16 + r16][kk + g * 8]);
            #pragma unroll
            for (int ni = 0; ni < 4; ni++)
                bfr[ni] = *reinterpret_cast<const short8*>(
                    &Wtp[(size_t)(wn * 64 + ni * 16 + r16) * D_IN + k0 + kk + g * 8]);
            #pragma unroll
            for (int mi = 0; mi < 2; mi++)
                #pragma unroll
                for (int ni = 0; ni < 4; ni++)
                    acc[mi][ni] = __builtin_amdgcn_mfma_f32_16x16x32_bf16(
                        af[mi], bfr[ni], acc[mi][ni], 0, 0, 0);
        }
        __syncthreads();
    }

    if (proj < 2) {
        unsigned short* out = (proj == 0) ? Qb : Kb;
        #pragma unroll
        for (int ni = 0; ni < 4; ni++) {
            int n = wn * 64 + ni * 16 + r16;
            float b = bias[n];
            #pragma unroll
            for (int mi = 0; mi < 2; mi++) {
                #pragma unroll
                for (int e = 0; e < 4; e++) {
                    int m = mb + wm * 32 + mi * 16 + g * 4 + e;
                    out[(size_t)m * DK + n] = f2bf(acc[mi][ni][e] + b);
                }
            }
        }
    } else {
        #pragma unroll
        for (int ni = 0; ni < 4; ni++) {
            int n = wn * 64 + ni * 16 + r16;
            float b = bias[n];
            #pragma unroll
            for (int mi = 0; mi < 2; mi++) {
                int m0 = mb + wm * 32 + mi * 16 + g * 4;
                ushort4 h;
                h.x = f2bf(acc[mi][ni][0] + b);
                h.y = f2bf(acc[mi][ni][1] + b);
                h.z = f2bf(acc[mi][ni][2] + b);
                h.w = f2bf(acc[mi][ni][3] + b);
                *reinterpret_cast<ushort4*>(&Vt[(size_t)n * N_TOK + m0]) = h;
            }
        }
    }
}

// ---------------- causal flash attention, swapped QK^T, KV-split partials --------
// S^T = mfma(K, Q): lane holds S^T[kv=ni*16+g*4+e][q=mi*16+r16] -> kv-reduction
// is 7 in-reg ops + shfl_xor(16,32). PV: O^T = mfma(V^T, P^T_lds).
__global__ __launch_bounds__(256) void attn_partial(
    const unsigned short* __restrict__ Qb, const unsigned short* __restrict__ Kb,
    const unsigned short* __restrict__ Vt,
    float* __restrict__ Opart, float* __restrict__ Mpart, float* __restrict__ Lpart,
    float* __restrict__ O, int chunk_tiles, int max_chunks, int direct)
{
    __shared__ float          O_merge[32][132];        // ~16.9 KB, f4-aligned rows
    __shared__ float          m_lds[4][32], l_lds[4][32];
    __shared__ unsigned short Pq[4][32][36];           // per-wave P[q][kv], pad 36

    const int t = blockIdx.x;
    const int c = blockIdx.y;
    const int j0 = c * chunk_tiles;
    if (j0 > t) return;
    const int jend = min(j0 + chunk_tiles, t + 1);

    const int tid = threadIdx.x;
    const int wid = tid >> 6, lane = tid & 63;
    const int g = lane >> 4, r16 = lane & 15;
    const int qbase = t * 32;
    const float scale = 0.08838834764831845f;  // 1/sqrt(128)

    // Q fragments (B-operand): col=q=mi*16+r16, k=d
    short8 qf[2][4];
    #pragma unroll
    for (int mi = 0; mi < 2; mi++)
        #pragma unroll
        for (int kd = 0; kd < 4; kd++)
            qf[mi][kd] = *reinterpret_cast<const short8*>(
                &Qb[(size_t)(qbase + mi * 16 + r16) * DK + kd * 32 + g * 8]);

    f32x4 o_acc[2][8] = {};                  // O^T: [q-frag mi][d-frag df]
    float m_run[2] = {-1e30f, -1e30f}, l_run[2] = {0.f, 0.f};

    for (int j = j0 + wid; j < jend; j += 4) {
        const int kvb = j * 32;
        // ---- S^T = K Q^T ----
        f32x4 st[2][2] = {};                 // [ni=kv frag][mi=q frag]
        #pragma unroll
        for (int kd = 0; kd < 4; kd++) {
            short8 kf[2];
            #pragma unroll
            for (int ni = 0; ni < 2; ni++)
                kf[ni] = *reinterpret_cast<const short8*>(
                    &Kb[(size_t)(kvb + ni * 16 + r16) * DK + kd * 32 + g * 8]);
            #pragma unroll
            for (int ni = 0; ni < 2; ni++)
                #pragma unroll
                for (int mi = 0; mi < 2; mi++)
                    st[ni][mi] = __builtin_amdgcn_mfma_f32_16x16x32_bf16(
                        kf[ni], qf[mi][kd], st[ni][mi], 0, 0, 0);
        }
        // ---- online softmax: per q-column (mi,r16); kv spread over (ni,e,g) ----
        float alpha[2];
        #pragma unroll
        for (int mi = 0; mi < 2; mi++) {
            float s[2][4];
            #pragma unroll
            for (int ni = 0; ni < 2; ni++)
                #pragma unroll
                for (int e = 0; e < 4; e++) {
                    float v = st[ni][mi][e] * scale;
                    if (j == t) {
                        int ql = mi * 16 + r16;
                        int kl = ni * 16 + g * 4 + e;
                        if (kl > ql) v = -1e30f;
                    }
                    s[ni][e] = v;
                }
            float lm = fmaxf(fmaxf(fmaxf(s[0][0], s[0][1]), fmaxf(s[0][2], s[0][3])),
                             fmaxf(fmaxf(s[1][0], s[1][1]), fmaxf(s[1][2], s[1][3])));
            lm = fmaxf(lm, __shfl_xor(lm, 16));
            lm = fmaxf(lm, __shfl_xor(lm, 32));
            float mnew = fmaxf(m_run[mi], lm);
            alpha[mi] = __expf(m_run[mi] - mnew);
            float ps[2][4], ls;
            #pragma unroll
            for (int ni = 0; ni < 2; ni++)
                #pragma unroll
                for (int e = 0; e < 4; e++)
                    ps[ni][e] = __expf(s[ni][e] - mnew);
            ls = ((ps[0][0] + ps[0][1]) + (ps[0][2] + ps[0][3]))
               + ((ps[1][0] + ps[1][1]) + (ps[1][2] + ps[1][3]));
            ls += __shfl_xor(ls, 16);
            ls += __shfl_xor(ls, 32);
            l_run[mi] = l_run[mi] * alpha[mi] + ls;
            m_run[mi] = mnew;
            // pack P[q][kv] into LDS: 8B per (mi,ni)
            #pragma unroll
            for (int ni = 0; ni < 2; ni++) {
                ushort4 pk;
                pk.x = f2bf(ps[ni][0]); pk.y = f2bf(ps[ni][1]);
                pk.z = f2bf(ps[ni][2]); pk.w = f2bf(ps[ni][3]);
                *reinterpret_cast<ushort4*>(&Pq[wid][mi * 16 + r16][ni * 16 + g * 4]) = pk;
            }
        }
        // rescale O^T accumulators (skip when no row max grew)
        if (__any(alpha[0] < 1.f) || __any(alpha[1] < 1.f)) {
            #pragma unroll
            for (int mi = 0; mi < 2; mi++)
                #pragma unroll
                for (int df = 0; df < 8; df++)
                    #pragma unroll
                    for (int e = 0; e < 4; e++)
                        o_acc[mi][df][e] *= alpha[mi];
        }
        // P^T B-fragments: col=q=r16, k=kv=g*8+idx
        short8 pb[2];
        pb[0] = *reinterpret_cast<const short8*>(&Pq[wid][r16][g * 8]);
        pb[1] = *reinterpret_cast<const short8*>(&Pq[wid][16 + r16][g * 8]);
        // ---- O^T += V^T P^T ----
        #pragma unroll
        for (int df = 0; df < 8; df++) {
            short8 vf = *reinterpret_cast<const short8*>(
                &Vt[(size_t)(df * 16 + r16) * N_TOK + kvb + g * 8]);
            o_acc[0][df] = __builtin_amdgcn_mfma_f32_16x16x32_bf16(vf, pb[0], o_acc[0][df], 0, 0, 0);
            o_acc[1][df] = __builtin_amdgcn_mfma_f32_16x16x32_bf16(vf, pb[1], o_acc[1][df], 0, 0, 0);
        }
    }

    // ---- merge the 4 wave partials ----
    if (g == 0) {
        #pragma unroll
        for (int mi = 0; mi < 2; mi++) {
            m_lds[wid][mi * 16 + r16] = m_run[mi];
            l_lds[wid][mi * 16 + r16] = l_run[mi];
        }
    }
    __syncthreads();
    float fscale[2];
    #pragma unroll
    for (int mi = 0; mi < 2; mi++) {
        int q = mi * 16 + r16;
        float M = fmaxf(fmaxf(m_lds[0][q], m_lds[1][q]),
                        fmaxf(m_lds[2][q], m_lds[3][q]));
        fscale[mi] = __expf(m_run[mi] - M);
    }
    for (int w = 0; w < 4; w++) {
        if (wid == w) {
            #pragma unroll
            for (int mi = 0; mi < 2; mi++) {
                int q = mi * 16 + r16;
                #pragma unroll
                for (int df = 0; df < 8; df++)
                    #pragma unroll
                    for (int e = 0; e < 4; e++) {
                        float v = o_acc[mi][df][e] * fscale[mi];
                        int d = df * 16 + g * 4 + e;
                        if (w == 0) O_merge[q][d] = v;
                        else        O_merge[q][d] += v;
                    }
            }
        }
        __syncthreads();
    }
    // ---- store partial (or direct) ----
    #pragma unroll
    for (int it = 0; it < 4; it++) {
        int idx = tid + it * 256;
        int row = idx >> 5, c4 = idx & 31;
        float M = fmaxf(fmaxf(m_lds[0][row], m_lds[1][row]),
                        fmaxf(m_lds[2][row], m_lds[3][row]));
        float L = 0.f;
        #pragma unroll
        for (int w = 0; w < 4; w++)
            L += __expf(m_lds[w][row] - M) * l_lds[w][row];
        float4 s = *reinterpret_cast<const float4*>(&O_merge[row][c4 * 4]);
        if (direct) {
            float inv = 1.0f / L;
            float4 r;
            r.x = s.x * inv; r.y = s.y * inv; r.z = s.z * inv; r.w = s.w * inv;
            *reinterpret_cast<float4*>(&O[(size_t)(qbase + row) * DK + c4 * 4]) = r;
        } else {
            size_t pb2 = ((size_t)t * max_chunks + c) * 32 + row;
            *reinterpret_cast<float4*>(&Opart[pb2 * 128 + c4 * 4]) = s;
            if (c4 == 0) { Mpart[pb2] = M; Lpart[pb2] = L; }
        }
    }
}

// ---------------- merge partials across chunks ----------------
__global__ __launch_bounds__(256) void attn_merge(
    const float* __restrict__ Opart, const float* __restrict__ Mpart,
    const float* __restrict__ Lpart, float* __restrict__ O,
    int chunk_tiles, int max_chunks)
{
    __shared__ float Ms[32], Ls[32], Fs[8][32];
    const int t = blockIdx.x;
    const int nc = t / chunk_tiles + 1;
    const int tid = threadIdx.x;

    if (tid < 32) {
        float M = -1e30f;
        for (int c = 0; c < nc; c++)
            M = fmaxf(M, Mpart[((size_t)t * max_chunks + c) * 32 + tid]);
        float L = 0.f;
        for (int c = 0; c < nc; c++) {
            size_t pb = ((size_t)t * max_chunks + c) * 32 + tid;
            L += __expf(Mpart[pb] - M) * Lpart[pb];
        }
        Ms[tid] = M; Ls[tid] = L;
    }
    __syncthreads();
    {
        int c = tid >> 5, row = tid & 31;
        if (c < nc)
            Fs[c][row] = __expf(Mpart[((size_t)t * max_chunks + c) * 32 + row] - Ms[row]);
    }
    __syncthreads();
    #pragma unroll
    for (int it = 0; it < 4; it++) {
        int idx = tid + it * 256;
        int row = idx >> 5, c4 = idx & 31;
        float4 acc = {0.f, 0.f, 0.f, 0.f};
        for (int c = 0; c < nc; c++) {
            const float4 v = *reinterpret_cast<const float4*>(
                &Opart[(((size_t)t * max_chunks + c) * 32 + row) * 128 + c4 * 4]);
            float f = Fs[c][row];
            acc.x += f * v.x; acc.y += f * v.y; acc.z += f * v.z; acc.w += f * v.w;
        }
        float inv = 1.0f / Ls[row];
        float4 r;
        r.x = acc.x * inv; r.y = acc.y * inv; r.z = acc.z * inv; r.w = acc.w * inv;
        *reinterpret_cast<float4*>(&O[((size_t)t * 32 + row) * DK + c4 * 4]) = r;
    }
}

extern "C" void kernel_launch(void* const* d_in, const int* in_sizes, int n_in,
                              void* d_out, int out_size, void* d_ws, size_t ws_size,
                              hipStream_t stream) {
    const float* X  = (const float*)d_in[0];
    const float* Wq = (const float*)d_in[1];
    const float* bq = (const float*)d_in[2];
    const float* Wk = (const float*)d_in[3];
    const float* bk = (const float*)d_in[4];
    const float* Wv = (const float*)d_in[5];
    const float* bv = (const float*)d_in[6];
    float* O = (float*)d_out;

    unsigned short* Qb = (unsigned short*)d_ws;
    unsigned short* Kb = Qb + (size_t)N_TOK * DK;
    unsigned short* Vt = Kb + (size_t)N_TOK * DK;
    unsigned short* Wt = Vt + (size_t)N_TOK * DK;
    float* Opart = (float*)(Wt + (size_t)3 * DK * D_IN);
    size_t base_bytes = (size_t)((char*)Opart - (char*)d_ws);

    int chunk_tiles = 0, max_chunks = 1, direct = 0;
    const int opts[4] = {32, 64, 128, 256};
    for (int i = 0; i < 4; i++) {
        int ct = opts[i], mc = NT / ct;
        size_t need = base_bytes + (size_t)NT * mc * 32 * (128 + 2) * sizeof(float);
        if (need <= ws_size) { chunk_tiles = ct; max_chunks = mc; break; }
    }
    if (!chunk_tiles) { chunk_tiles = NT; max_chunks = 1; direct = 1; }
    float* Mpart = Opart + (size_t)NT * max_chunks * 32 * 128;
    float* Lpart = Mpart + (size_t)NT * max_chunks * 32;

    wtrans_kernel<<<dim3(32, 3), 256, 0, stream>>>(Wq, Wk, Wv, Wt);
    proj_kernel<<<dim3(128, 3), 256, 0, stream>>>(X, Wt, bq, bk, bv, Qb, Kb, Vt);
    attn_partial<<<dim3(NT, max_chunks), 256, 0, stream>>>(
        Qb, Kb, Vt, Opart, Mpart, Lpart, O, chunk_tiles, max_chunks, direct);
    if (!direct)
        attn_merge<<<dim3(NT), 256, 0, stream>>>(Opart, Mpart, Lpart, O,
                                                 chunk_tiles, max_chunks);
}